// Round 7
// baseline (371.501 us; speedup 1.0000x reference)
//
#include <hip/hip_runtime.h>
#include <math.h>

#define PI_F 3.14159265358979323846f
#define BSTRIDE 404   // basis row stride (400 taps + 4 zero pad)

// ---------------------------------------------------------------------------
// Prep: softmax over sub-axis (also to d_out), CsT in BLOCKED float4 layout
// CsTb[e/64][s4][e%64] = {p*sc for s=s4*4..s4*4+3}  (coalesced 1KB wave loads
// in syn), zero-padded to 2048 / 256 e-rows, and the 24x404 masked cos-basis.
// ---------------------------------------------------------------------------
__global__ __launch_bounds__(256) void prep_kernel(
    const float* __restrict__ Ce_raw, const float* __restrict__ Ci_raw,
    const float* __restrict__ Escale, const float* __restrict__ Iscale,
    const float* __restrict__ temp,
    float4* __restrict__ CbE, float4* __restrict__ CbI,
    float* __restrict__ basis,
    float* __restrict__ outCe, float* __restrict__ outCi)
{
    int id = blockIdx.x * 256 + threadIdx.x;
    if (id < 2000) {
        int e = id;
        float t = temp[0];
        float v[20];
        float m = -1e30f;
        #pragma unroll
        for (int s = 0; s < 20; ++s) { v[s] = Ce_raw[s * 2000 + e] / t; m = fmaxf(m, v[s]); }
        float sum = 0.f;
        #pragma unroll
        for (int s = 0; s < 20; ++s) { v[s] = expf(v[s] - m); sum += v[s]; }
        float inv = 1.f / sum;
        float sc = expf(Escale[e]);
        int bi = (e >> 6) * 5, ln = e & 63;
        #pragma unroll
        for (int s4 = 0; s4 < 5; ++s4) {
            float p0 = v[s4*4+0] * inv, p1 = v[s4*4+1] * inv;
            float p2 = v[s4*4+2] * inv, p3 = v[s4*4+3] * inv;
            outCe[(s4*4+0) * 2000 + e] = p0;
            outCe[(s4*4+1) * 2000 + e] = p1;
            outCe[(s4*4+2) * 2000 + e] = p2;
            outCe[(s4*4+3) * 2000 + e] = p3;
            CbE[(bi + s4) * 64 + ln] = make_float4(p0*sc, p1*sc, p2*sc, p3*sc);
        }
    } else if (id < 2200) {
        int e = id - 2000;
        float t = temp[0];
        float v[20];
        float m = -1e30f;
        #pragma unroll
        for (int s = 0; s < 20; ++s) { v[s] = Ci_raw[s * 200 + e] / t; m = fmaxf(m, v[s]); }
        float sum = 0.f;
        #pragma unroll
        for (int s = 0; s < 20; ++s) { v[s] = expf(v[s] - m); sum += v[s]; }
        float inv = 1.f / sum;
        float sc = expf(Iscale[e]);
        int bi = (e >> 6) * 5, ln = e & 63;
        #pragma unroll
        for (int s4 = 0; s4 < 5; ++s4) {
            float p0 = v[s4*4+0] * inv, p1 = v[s4*4+1] * inv;
            float p2 = v[s4*4+2] * inv, p3 = v[s4*4+3] * inv;
            outCi[(s4*4+0) * 200 + e] = p0;
            outCi[(s4*4+1) * 200 + e] = p1;
            outCi[(s4*4+2) * 200 + e] = p2;
            outCi[(s4*4+3) * 200 + e] = p3;
            CbI[(bi + s4) * 64 + ln] = make_float4(p0*sc, p1*sc, p2*sc, p3*sc);
        }
    } else if (id < 2200 + 24 * BSTRIDE) {
        int idx = id - 2200;
        int j = idx / BSTRIDE, d = idx - j * BSTRIDE;
        float val = 0.f;
        if (d < 400) {
            float raw = 6.0f * logf((float)d + 1.0f + 1e-7f);
            float ph = (PI_F * 0.5f) * (float)j;
            if (raw >= ph - PI_F && raw <= ph + PI_F) val = 0.5f * cosf(raw - ph) + 0.5f;
        }
        basis[idx] = val;
    } else if (id < 11896 + 48) {               // CbE pad rows 2000..2047
        int e = 2000 + (id - 11896);
        int bi = (e >> 6) * 5, ln = e & 63;
        #pragma unroll
        for (int s4 = 0; s4 < 5; ++s4)
            CbE[(bi + s4) * 64 + ln] = make_float4(0.f, 0.f, 0.f, 0.f);
    } else if (id < 11944 + 56) {               // CbI pad rows 200..255
        int e = 200 + (id - 11944);
        int bi = (e >> 6) * 5, ln = e & 63;
        #pragma unroll
        for (int s4 = 0; s4 < 5; ++s4)
            CbI[(bi + s4) * 64 + ln] = make_float4(0.f, 0.f, 0.f, 0.f);
    }
}

// ---------------------------------------------------------------------------
// syn einsum, streaming row-quad: wave owns 4 rows (b,t); lane owns e-slot
// eb*64+lane. S loads coalesced dwords; CsT loads coalesced float4 from the
// blocked layout (pure VMEM: no LDS, no barriers, no SMEM/DS lgkmcnt mixing).
// Epilogue: 6-level shfl_xor allreduce, lane 0 stores 80 values.
// ---------------------------------------------------------------------------
template <int NFULL>
__global__ __launch_bounds__(256) void syn_kernel(
    const float* __restrict__ S, const float4* __restrict__ Cb,
    float* __restrict__ syn, int Eno)
{
    const int lane = threadIdx.x & 63;
    const int gw = blockIdx.x * 4 + (threadIdx.x >> 6);
    const int r0 = gw * 4;
    const size_t sb = (size_t)r0 * Eno;

    float acc[4][20];
    #pragma unroll
    for (int m = 0; m < 4; ++m)
        #pragma unroll
        for (int s = 0; s < 20; ++s) acc[m][s] = 0.f;

    const float4* cbl = Cb + lane;

    #pragma unroll 2
    for (int eb = 0; eb < NFULL; ++eb) {
        const int e = eb * 64 + lane;
        float sv[4];
        sv[0] = S[sb + e];
        sv[1] = S[sb + (size_t)Eno + e];
        sv[2] = S[sb + (size_t)(2 * Eno) + e];
        sv[3] = S[sb + (size_t)(3 * Eno) + e];
        float4 c[5];
        #pragma unroll
        for (int s4 = 0; s4 < 5; ++s4) c[s4] = cbl[(eb * 5 + s4) * 64];
        #pragma unroll
        for (int m = 0; m < 4; ++m) {
            float s_ = sv[m];
            #pragma unroll
            for (int s4 = 0; s4 < 5; ++s4) {
                acc[m][s4*4+0] = fmaf(s_, c[s4].x, acc[m][s4*4+0]);
                acc[m][s4*4+1] = fmaf(s_, c[s4].y, acc[m][s4*4+1]);
                acc[m][s4*4+2] = fmaf(s_, c[s4].z, acc[m][s4*4+2]);
                acc[m][s4*4+3] = fmaf(s_, c[s4].w, acc[m][s4*4+3]);
            }
        }
    }
    {   // tail block: lanes with e >= Eno contribute 0
        const int e = NFULL * 64 + lane;
        const bool ok = e < Eno;
        float sv[4];
        sv[0] = ok ? S[sb + e] : 0.f;
        sv[1] = ok ? S[sb + (size_t)Eno + e] : 0.f;
        sv[2] = ok ? S[sb + (size_t)(2 * Eno) + e] : 0.f;
        sv[3] = ok ? S[sb + (size_t)(3 * Eno) + e] : 0.f;
        float4 c[5];
        #pragma unroll
        for (int s4 = 0; s4 < 5; ++s4) c[s4] = cbl[(NFULL * 5 + s4) * 64];
        #pragma unroll
        for (int m = 0; m < 4; ++m) {
            float s_ = sv[m];
            #pragma unroll
            for (int s4 = 0; s4 < 5; ++s4) {
                acc[m][s4*4+0] = fmaf(s_, c[s4].x, acc[m][s4*4+0]);
                acc[m][s4*4+1] = fmaf(s_, c[s4].y, acc[m][s4*4+1]);
                acc[m][s4*4+2] = fmaf(s_, c[s4].z, acc[m][s4*4+2]);
                acc[m][s4*4+3] = fmaf(s_, c[s4].w, acc[m][s4*4+3]);
            }
        }
    }

    #pragma unroll
    for (int m = 0; m < 4; ++m)
        #pragma unroll
        for (int s = 0; s < 20; ++s) {
            float v = acc[m][s];
            v += __shfl_xor(v, 32);
            v += __shfl_xor(v, 16);
            v += __shfl_xor(v, 8);
            v += __shfl_xor(v, 4);
            v += __shfl_xor(v, 2);
            v += __shfl_xor(v, 1);
            acc[m][s] = v;
        }

    if (lane == 0) {
        const int b = r0 / 5000;
        const int t = r0 - b * 5000;              // rows r0..r0+3 share b
        #pragma unroll
        for (int m = 0; m < 4; ++m)
            #pragma unroll
            for (int s = 0; s < 20; ++s)
                syn[((size_t)b * 20 + s) * 5000 + t + m] = acc[m][s];
    }
}

// ---------------------------------------------------------------------------
// Fused basis-conv + layer1(tanh) + layer2 reduce.  (unchanged from round 6)
// Bit-rotate LDS swizzle: phys4(g) = (g&~15)|((g>>1)&7)|((g&1)<<3) -> stride-2
// fixed-parity b128 reads conflict-free; phys4(g+1)=phys4(g)+8.
// Unroll-8 two-bank software pipeline, 3-body load lookahead.
// ---------------------------------------------------------------------------
__device__ const int CJ_LO[24] = {0,0,0,0,0,0,0,0,0,4,4,8,12,16,20,28,36,48,64,84,108,140,184,240};
__device__ const int CJ_NB[24] = {1,1,1,1,2,2,3,3,4,4,5,6,7,9,12,15,19,25,31,41,53,65,54,40};

__device__ __forceinline__ int phys4(int g) {
    return (g & ~15) | ((g >> 1) & 7) | ((g & 1) << 3);
}

__global__ __launch_bounds__(128) void conv_kernel(
    const float* __restrict__ syn_e, const float* __restrict__ syn_i,
    const float* __restrict__ basis,
    const float* __restrict__ W_e, const float* __restrict__ W_i,
    const float* __restrict__ b1, const float* __restrict__ W2,
    float* __restrict__ sub_out)
{
    __shared__ float4 win4[16 + 464];             // 16-granule guard + window
    float4* wbase = win4 + 16;
    float2* win2 = reinterpret_cast<float2*>(wbase);
    const int tid = threadIdx.x;
    const int tile = blockIdx.x, s = blockIdx.y, bz = blockIdx.z;
    const int t0 = tile * 512;

    const float* se = syn_e + ((size_t)bz * 20 + s) * 5000;
    const float* si = syn_i + ((size_t)bz * 20 + s) * 5000;
    for (int l = tid; l < 920; l += 128) {
        int t = t0 - 404 + l;
        float ve = 0.f, vi = 0.f;
        if ((unsigned)t < 5000u) { ve = se[t]; vi = si[t]; }
        int g = l >> 1;
        win2[2 * phys4(g) + (l & 1)] = make_float2(ve, vi);
    }
    __syncthreads();

    float z[16][4];
    #pragma unroll
    for (int h = 0; h < 16; ++h) {
        float bv = b1[s * 16 + h];
        #pragma unroll
        for (int k = 0; k < 4; ++k) z[h][k] = bv;
    }

    const int base = 4 * tid + 400;

    for (int j = 0; j < 24; ++j) {
        const float4* bj4 = reinterpret_cast<const float4*>(basis + j * BSTRIDE);
        const int lo = CJ_LO[j];
        const int nb = CJ_NB[j];
        const int co = lo >> 2;
        float be0 = 0.f, be1 = 0.f, be2 = 0.f, be3 = 0.f;
        float bi0 = 0.f, bi1 = 0.f, bi2 = 0.f, bi3 = 0.f;

        auto body = [&](const float4& V0, const float4& V1,
                        const float4& V2, const float4& V3, const float4& c) {
            be0 = fmaf(c.x, V2.x, be0); bi0 = fmaf(c.x, V2.y, bi0);
            be1 = fmaf(c.x, V2.z, be1); bi1 = fmaf(c.x, V2.w, bi1);
            be2 = fmaf(c.x, V3.x, be2); bi2 = fmaf(c.x, V3.y, bi2);
            be3 = fmaf(c.x, V3.z, be3); bi3 = fmaf(c.x, V3.w, bi3);
            be0 = fmaf(c.y, V1.z, be0); bi0 = fmaf(c.y, V1.w, bi0);
            be1 = fmaf(c.y, V2.x, be1); bi1 = fmaf(c.y, V2.y, bi1);
            be2 = fmaf(c.y, V2.z, be2); bi2 = fmaf(c.y, V2.w, bi2);
            be3 = fmaf(c.y, V3.x, be3); bi3 = fmaf(c.y, V3.y, bi3);
            be0 = fmaf(c.z, V1.x, be0); bi0 = fmaf(c.z, V1.y, bi0);
            be1 = fmaf(c.z, V1.z, be1); bi1 = fmaf(c.z, V1.w, bi1);
            be2 = fmaf(c.z, V2.x, be2); bi2 = fmaf(c.z, V2.y, bi2);
            be3 = fmaf(c.z, V2.z, be3); bi3 = fmaf(c.z, V2.w, bi3);
            be0 = fmaf(c.w, V0.z, be0); bi0 = fmaf(c.w, V0.w, bi0);
            be1 = fmaf(c.w, V1.x, be1); bi1 = fmaf(c.w, V1.y, bi1);
            be2 = fmaf(c.w, V1.z, be2); bi2 = fmaf(c.w, V1.w, bi2);
            be3 = fmaf(c.w, V2.x, be3); bi3 = fmaf(c.w, V2.y, bi3);
        };

        const int g0 = (base - lo) >> 1;          // even
        auto LP = [&](int n, float4& lo4, float4& hi4) {
            int p = phys4(g0 - 2 * n);
            lo4 = wbase[p]; hi4 = wbase[p + 8];
        };

        float4 A0, A1, B0, B1, C0, C1, D0, D1;
        float4 E0, E1, F0, F1, G0, G1, H0, H1;
        LP(-1, A0, A1); LP(0, B0, B1); LP(1, C0, C1); LP(2, D0, D1);
        float4 cB = bj4[co], cC = bj4[co + 1], cD = bj4[co + 2];

        int bb = 0;
        while (bb + 8 <= nb) {
            LP(bb + 3, E0, E1); float4 cE = bj4[co + bb + 3];
            body(B0, B1, A0, A1, cB);
            LP(bb + 4, F0, F1); float4 cF = bj4[co + bb + 4];
            body(C0, C1, B0, B1, cC);
            LP(bb + 5, G0, G1); float4 cG = bj4[co + bb + 5];
            body(D0, D1, C0, C1, cD);
            LP(bb + 6, H0, H1); float4 cH = bj4[co + bb + 6];
            body(E0, E1, D0, D1, cE);
            LP(bb + 7, A0, A1); float4 cI = bj4[co + bb + 7];
            body(F0, F1, E0, E1, cF);
            LP(bb + 8, B0, B1); cB = bj4[co + bb + 8];
            body(G0, G1, F0, F1, cG);
            LP(bb + 9, C0, C1); cC = bj4[co + bb + 9];
            body(H0, H1, G0, G1, cH);
            LP(bb + 10, D0, D1); cD = bj4[co + bb + 10];
            body(A0, A1, H0, H1, cI);
            bb += 8;
        }
        int r = nb - bb;
        if (r > 0) { body(B0, B1, A0, A1, cB);
          if (r > 1) { body(C0, C1, B0, B1, cC);
            if (r > 2) { body(D0, D1, C0, C1, cD);
              if (r > 3) { LP(bb + 3, E0, E1); float4 cE = bj4[co + bb + 3];
                body(E0, E1, D0, D1, cE);
                if (r > 4) { LP(bb + 4, F0, F1); float4 cF = bj4[co + bb + 4];
                  body(F0, F1, E0, E1, cF);
                  if (r > 5) { LP(bb + 5, G0, G1); float4 cG = bj4[co + bb + 5];
                    body(G0, G1, F0, F1, cG);
                    if (r > 6) { LP(bb + 6, H0, H1); float4 cH = bj4[co + bb + 6];
                      body(H0, H1, G0, G1, cH); } } } } } } }

        #pragma unroll
        for (int h = 0; h < 16; ++h) {
            float we = W_e[(s * 16 + h) * 24 + j];
            float wi = W_i[(s * 16 + h) * 24 + j];
            z[h][0] = fmaf(we, be0, fmaf(wi, bi0, z[h][0]));
            z[h][1] = fmaf(we, be1, fmaf(wi, bi1, z[h][1]));
            z[h][2] = fmaf(we, be2, fmaf(wi, bi2, z[h][2]));
            z[h][3] = fmaf(we, be3, fmaf(wi, bi3, z[h][3]));
        }
    }

    float w2v[16];
    #pragma unroll
    for (int h = 0; h < 16; ++h) w2v[h] = __expf(W2[s * 16 + h]);

    #pragma unroll
    for (int k = 0; k < 4; ++k) {
        int t = t0 + 4 * tid + k;
        if (t < 5000) {
            float acc = 0.f;
            #pragma unroll
            for (int h = 0; h < 16; ++h) {
                float e2 = __expf(2.0f * z[h][k]);
                float th = 1.0f - 2.0f / (e2 + 1.0f);
                acc = fmaf(w2v[h], th, acc);
            }
            sub_out[((size_t)bz * 5000 + t) * 20 + s] = acc;
        }
    }
}

// ---------------------------------------------------------------------------
// final[b,t] = V_o + sum_s sub_out[b,t,s]
// ---------------------------------------------------------------------------
__global__ __launch_bounds__(256) void final_kernel(
    const float* __restrict__ sub_out, const float* __restrict__ V_o,
    float* __restrict__ fin)
{
    int r = blockIdx.x * 256 + threadIdx.x;
    if (r < 40000) {
        const float* p = sub_out + (size_t)r * 20;
        float a = V_o[0];
        #pragma unroll
        for (int s = 0; s < 20; ++s) a += p[s];
        fin[r] = a;
    }
}

extern "C" void kernel_launch(void* const* d_in, const int* in_sizes, int n_in,
                              void* d_out, int out_size, void* d_ws, size_t ws_size,
                              hipStream_t stream)
{
    const float* S_e     = (const float*)d_in[0];
    const float* S_i     = (const float*)d_in[1];
    const float* E_scale = (const float*)d_in[2];
    const float* I_scale = (const float*)d_in[3];
    const float* W_e     = (const float*)d_in[4];
    const float* W_i     = (const float*)d_in[5];
    const float* W2      = (const float*)d_in[6];
    const float* b1      = (const float*)d_in[7];
    const float* Ce_raw  = (const float*)d_in[8];
    const float* Ci_raw  = (const float*)d_in[9];
    const float* V_o     = (const float*)d_in[10];
    const float* temp    = (const float*)d_in[11];

    float* out     = (float*)d_out;
    float* fin     = out;              // 40000
    float* sub_out = out + 40000;      // 800000
    float* outCe   = out + 840000;     // 40000
    float* outCi   = out + 880000;     // 4000

    float* ws    = (float*)d_ws;
    float4* CbE  = (float4*)ws;        // 32 blk x 5 x 64 float4 = 40960 floats
    float4* CbI  = (float4*)(ws + 40960); // 4 blk x 5 x 64 = 5120 floats
    float* basis = ws + 46080;         // 24*404 = 9696
    float* syn_e = ws + 55776;         // 800000
    float* syn_i = ws + 855776;        // 800000

    prep_kernel<<<47, 256, 0, stream>>>(Ce_raw, Ci_raw, E_scale, I_scale, temp,
                                        CbE, CbI, basis, outCe, outCi);
    syn_kernel<31><<<2500, 256, 0, stream>>>(S_e, CbE, syn_e, 2000);
    syn_kernel<3><<<2500, 256, 0, stream>>>(S_i, CbI, syn_i, 200);
    conv_kernel<<<dim3(10, 20, 8), 128, 0, stream>>>(syn_e, syn_i, basis,
                                                     W_e, W_i, b1, W2, sub_out);
    final_kernel<<<157, 256, 0, stream>>>(sub_out, V_o, fin);
}

// Round 8
// 361.311 us; speedup vs baseline: 1.0282x; 1.0282x over previous
//
#include <hip/hip_runtime.h>
#include <math.h>

#define PI_F 3.14159265358979323846f
#define BSTRIDE 404   // basis row stride (400 taps + 4 zero pad)

// ---------------------------------------------------------------------------
// Prep: softmax over sub-axis (also to d_out), CsT in BLOCKED float4 layout
// Cb[e/64][s4][e%64] = {p*sc for s=s4*4..s4*4+3}, zero-padded to 2048 / 256
// e-rows, and the 24x404 masked cos-basis table.
// ---------------------------------------------------------------------------
__global__ __launch_bounds__(256) void prep_kernel(
    const float* __restrict__ Ce_raw, const float* __restrict__ Ci_raw,
    const float* __restrict__ Escale, const float* __restrict__ Iscale,
    const float* __restrict__ temp,
    float4* __restrict__ CbE, float4* __restrict__ CbI,
    float* __restrict__ basis,
    float* __restrict__ outCe, float* __restrict__ outCi)
{
    int id = blockIdx.x * 256 + threadIdx.x;
    if (id < 2000) {
        int e = id;
        float t = temp[0];
        float v[20];
        float m = -1e30f;
        #pragma unroll
        for (int s = 0; s < 20; ++s) { v[s] = Ce_raw[s * 2000 + e] / t; m = fmaxf(m, v[s]); }
        float sum = 0.f;
        #pragma unroll
        for (int s = 0; s < 20; ++s) { v[s] = expf(v[s] - m); sum += v[s]; }
        float inv = 1.f / sum;
        float sc = expf(Escale[e]);
        int bi = (e >> 6) * 5, ln = e & 63;
        #pragma unroll
        for (int s4 = 0; s4 < 5; ++s4) {
            float p0 = v[s4*4+0] * inv, p1 = v[s4*4+1] * inv;
            float p2 = v[s4*4+2] * inv, p3 = v[s4*4+3] * inv;
            outCe[(s4*4+0) * 2000 + e] = p0;
            outCe[(s4*4+1) * 2000 + e] = p1;
            outCe[(s4*4+2) * 2000 + e] = p2;
            outCe[(s4*4+3) * 2000 + e] = p3;
            CbE[(bi + s4) * 64 + ln] = make_float4(p0*sc, p1*sc, p2*sc, p3*sc);
        }
    } else if (id < 2200) {
        int e = id - 2000;
        float t = temp[0];
        float v[20];
        float m = -1e30f;
        #pragma unroll
        for (int s = 0; s < 20; ++s) { v[s] = Ci_raw[s * 200 + e] / t; m = fmaxf(m, v[s]); }
        float sum = 0.f;
        #pragma unroll
        for (int s = 0; s < 20; ++s) { v[s] = expf(v[s] - m); sum += v[s]; }
        float inv = 1.f / sum;
        float sc = expf(Iscale[e]);
        int bi = (e >> 6) * 5, ln = e & 63;
        #pragma unroll
        for (int s4 = 0; s4 < 5; ++s4) {
            float p0 = v[s4*4+0] * inv, p1 = v[s4*4+1] * inv;
            float p2 = v[s4*4+2] * inv, p3 = v[s4*4+3] * inv;
            outCi[(s4*4+0) * 200 + e] = p0;
            outCi[(s4*4+1) * 200 + e] = p1;
            outCi[(s4*4+2) * 200 + e] = p2;
            outCi[(s4*4+3) * 200 + e] = p3;
            CbI[(bi + s4) * 64 + ln] = make_float4(p0*sc, p1*sc, p2*sc, p3*sc);
        }
    } else if (id < 2200 + 24 * BSTRIDE) {
        int idx = id - 2200;
        int j = idx / BSTRIDE, d = idx - j * BSTRIDE;
        float val = 0.f;
        if (d < 400) {
            float raw = 6.0f * logf((float)d + 1.0f + 1e-7f);
            float ph = (PI_F * 0.5f) * (float)j;
            if (raw >= ph - PI_F && raw <= ph + PI_F) val = 0.5f * cosf(raw - ph) + 0.5f;
        }
        basis[idx] = val;
    } else if (id < 11896 + 48) {               // CbE pad rows 2000..2047
        int e = 2000 + (id - 11896);
        int bi = (e >> 6) * 5, ln = e & 63;
        #pragma unroll
        for (int s4 = 0; s4 < 5; ++s4)
            CbE[(bi + s4) * 64 + ln] = make_float4(0.f, 0.f, 0.f, 0.f);
    } else if (id < 11944 + 56) {               // CbI pad rows 200..255
        int e = 200 + (id - 11944);
        int bi = (e >> 6) * 5, ln = e & 63;
        #pragma unroll
        for (int s4 = 0; s4 < 5; ++s4)
            CbI[(bi + s4) * 64 + ln] = make_float4(0.f, 0.f, 0.f, 0.f);
    }
}

// ---------------------------------------------------------------------------
// syn einsum v8: wave owns 4 rows, lane owns e-slot eb*64+lane.
// Cb staged through LDS double-buffer cb[2][64][20] (10 KB): coalesced 1KB
// global loads once per BLOCK per chunk; compute reads ds_read_b128 at
// lane-stride 20 words (bank-quad = lane*5 mod 8 -> conflict-free).
// S: 2-deep register prefetch (sv0/sv1/sv2) so HBM loads stay in flight
// across the 80-FMA phase. One barrier per chunk. Epilogue: shfl_xor
// allreduce, lane 0 stores.
// NT = total 64-e chunks (Cb zero-padded to NT*64 rows); S guarded in tail.
// ---------------------------------------------------------------------------
template <int NT>
__global__ __launch_bounds__(256, 3) void syn_kernel(
    const float* __restrict__ S, const float4* __restrict__ Cb,
    float* __restrict__ syn, int Eno)
{
    __shared__ float cb[2][64][20];               // 10240 B
    const int tid = threadIdx.x;
    const int lane = tid & 63;
    const int gw = blockIdx.x * 4 + (tid >> 6);
    const int r0 = gw * 4;
    const size_t sb = (size_t)r0 * Eno;

    float acc[4][20];
    #pragma unroll
    for (int m = 0; m < 4; ++m)
        #pragma unroll
        for (int s = 0; s < 20; ++s) acc[m][s] = 0.f;

    const int ss4 = tid >> 6;                     // stage role: s4 = wave id
    const int sln = tid & 63;

    // issue S loads for chunk q (guarded; q >= NT -> all zero)
    auto ldS = [&](int q, float (&sv)[4]) {
        int e = q * 64 + lane;
        bool ok = (q < NT) && (e < Eno);
        sv[0] = ok ? S[sb + e] : 0.f;
        sv[1] = ok ? S[sb + (size_t)Eno + e] : 0.f;
        sv[2] = ok ? S[sb + (size_t)(2 * Eno) + e] : 0.f;
        sv[3] = ok ? S[sb + (size_t)(3 * Eno) + e] : 0.f;
    };

    // prologue: chunks 0,1 into LDS; S prefetch 2-deep
    float sv0[4], sv1[4], sv2[4];
    ldS(0, sv0);
    ldS(1, sv1);
    {
        float4 a = Cb[(0 * 5 + ss4) * 64 + sln];
        float4 b = Cb[(1 * 5 + ss4) * 64 + sln];
        *reinterpret_cast<float4*>(&cb[0][sln][ss4 * 4]) = a;
        *reinterpret_cast<float4*>(&cb[1][sln][ss4 * 4]) = b;
        if (tid < 64) {
            float4 a4 = Cb[(0 * 5 + 4) * 64 + sln];
            float4 b4 = Cb[(1 * 5 + 4) * 64 + sln];
            *reinterpret_cast<float4*>(&cb[0][sln][16]) = a4;
            *reinterpret_cast<float4*>(&cb[1][sln][16]) = b4;
        }
    }
    __syncthreads();

    int buf = 0;
    for (int eb = 0; eb < NT; ++eb) {
        // early-issue: S for eb+2, Cb for eb+2 (ds_write deferred past barrier)
        ldS(eb + 2, sv2);
        const bool have = (eb + 2) < NT;
        float4 sg0, sg1;
        if (have) {
            sg0 = Cb[((eb + 2) * 5 + ss4) * 64 + sln];
            if (tid < 64) sg1 = Cb[((eb + 2) * 5 + 4) * 64 + sln];
        }

        // compute chunk eb from cb[buf] with sv0
        float4 c[5];
        #pragma unroll
        for (int s4 = 0; s4 < 5; ++s4)
            c[s4] = *reinterpret_cast<const float4*>(&cb[buf][lane][s4 * 4]);
        #pragma unroll
        for (int m = 0; m < 4; ++m) {
            float s_ = sv0[m];
            #pragma unroll
            for (int s4 = 0; s4 < 5; ++s4) {
                acc[m][s4*4+0] = fmaf(s_, c[s4].x, acc[m][s4*4+0]);
                acc[m][s4*4+1] = fmaf(s_, c[s4].y, acc[m][s4*4+1]);
                acc[m][s4*4+2] = fmaf(s_, c[s4].z, acc[m][s4*4+2]);
                acc[m][s4*4+3] = fmaf(s_, c[s4].w, acc[m][s4*4+3]);
            }
        }

        __syncthreads();                 // all reads of cb[buf] done block-wide
        if (have) {
            *reinterpret_cast<float4*>(&cb[buf][sln][ss4 * 4]) = sg0;
            if (tid < 64)
                *reinterpret_cast<float4*>(&cb[buf][sln][16]) = sg1;
        }
        buf ^= 1;

        #pragma unroll
        for (int k = 0; k < 4; ++k) { sv0[k] = sv1[k]; sv1[k] = sv2[k]; }
    }

    #pragma unroll
    for (int m = 0; m < 4; ++m)
        #pragma unroll
        for (int s = 0; s < 20; ++s) {
            float v = acc[m][s];
            v += __shfl_xor(v, 32);
            v += __shfl_xor(v, 16);
            v += __shfl_xor(v, 8);
            v += __shfl_xor(v, 4);
            v += __shfl_xor(v, 2);
            v += __shfl_xor(v, 1);
            acc[m][s] = v;
        }

    if (lane == 0) {
        const int b = r0 / 5000;
        const int t = r0 - b * 5000;              // rows r0..r0+3 share b
        #pragma unroll
        for (int m = 0; m < 4; ++m)
            #pragma unroll
            for (int s = 0; s < 20; ++s)
                syn[((size_t)b * 20 + s) * 5000 + t + m] = acc[m][s];
    }
}

// ---------------------------------------------------------------------------
// Fused basis-conv + layer1(tanh) + layer2 reduce.  (unchanged)
// Bit-rotate LDS swizzle phys4; unroll-8 two-bank pipeline, 3-body lookahead.
// ---------------------------------------------------------------------------
__device__ const int CJ_LO[24] = {0,0,0,0,0,0,0,0,0,4,4,8,12,16,20,28,36,48,64,84,108,140,184,240};
__device__ const int CJ_NB[24] = {1,1,1,1,2,2,3,3,4,4,5,6,7,9,12,15,19,25,31,41,53,65,54,40};

__device__ __forceinline__ int phys4(int g) {
    return (g & ~15) | ((g >> 1) & 7) | ((g & 1) << 3);
}

__global__ __launch_bounds__(128) void conv_kernel(
    const float* __restrict__ syn_e, const float* __restrict__ syn_i,
    const float* __restrict__ basis,
    const float* __restrict__ W_e, const float* __restrict__ W_i,
    const float* __restrict__ b1, const float* __restrict__ W2,
    float* __restrict__ sub_out)
{
    __shared__ float4 win4[16 + 464];             // 16-granule guard + window
    float4* wbase = win4 + 16;
    float2* win2 = reinterpret_cast<float2*>(wbase);
    const int tid = threadIdx.x;
    const int tile = blockIdx.x, s = blockIdx.y, bz = blockIdx.z;
    const int t0 = tile * 512;

    const float* se = syn_e + ((size_t)bz * 20 + s) * 5000;
    const float* si = syn_i + ((size_t)bz * 20 + s) * 5000;
    for (int l = tid; l < 920; l += 128) {
        int t = t0 - 404 + l;
        float ve = 0.f, vi = 0.f;
        if ((unsigned)t < 5000u) { ve = se[t]; vi = si[t]; }
        int g = l >> 1;
        win2[2 * phys4(g) + (l & 1)] = make_float2(ve, vi);
    }
    __syncthreads();

    float z[16][4];
    #pragma unroll
    for (int h = 0; h < 16; ++h) {
        float bv = b1[s * 16 + h];
        #pragma unroll
        for (int k = 0; k < 4; ++k) z[h][k] = bv;
    }

    const int base = 4 * tid + 400;

    for (int j = 0; j < 24; ++j) {
        const float4* bj4 = reinterpret_cast<const float4*>(basis + j * BSTRIDE);
        const int lo = CJ_LO[j];
        const int nb = CJ_NB[j];
        const int co = lo >> 2;
        float be0 = 0.f, be1 = 0.f, be2 = 0.f, be3 = 0.f;
        float bi0 = 0.f, bi1 = 0.f, bi2 = 0.f, bi3 = 0.f;

        auto body = [&](const float4& V0, const float4& V1,
                        const float4& V2, const float4& V3, const float4& c) {
            be0 = fmaf(c.x, V2.x, be0); bi0 = fmaf(c.x, V2.y, bi0);
            be1 = fmaf(c.x, V2.z, be1); bi1 = fmaf(c.x, V2.w, bi1);
            be2 = fmaf(c.x, V3.x, be2); bi2 = fmaf(c.x, V3.y, bi2);
            be3 = fmaf(c.x, V3.z, be3); bi3 = fmaf(c.x, V3.w, bi3);
            be0 = fmaf(c.y, V1.z, be0); bi0 = fmaf(c.y, V1.w, bi0);
            be1 = fmaf(c.y, V2.x, be1); bi1 = fmaf(c.y, V2.y, bi1);
            be2 = fmaf(c.y, V2.z, be2); bi2 = fmaf(c.y, V2.w, bi2);
            be3 = fmaf(c.y, V3.x, be3); bi3 = fmaf(c.y, V3.y, bi3);
            be0 = fmaf(c.z, V1.x, be0); bi0 = fmaf(c.z, V1.y, bi0);
            be1 = fmaf(c.z, V1.z, be1); bi1 = fmaf(c.z, V1.w, bi1);
            be2 = fmaf(c.z, V2.x, be2); bi2 = fmaf(c.z, V2.y, bi2);
            be3 = fmaf(c.z, V2.z, be3); bi3 = fmaf(c.z, V2.w, bi3);
            be0 = fmaf(c.w, V0.z, be0); bi0 = fmaf(c.w, V0.w, bi0);
            be1 = fmaf(c.w, V1.x, be1); bi1 = fmaf(c.w, V1.y, bi1);
            be2 = fmaf(c.w, V1.z, be2); bi2 = fmaf(c.w, V1.w, bi2);
            be3 = fmaf(c.w, V2.x, be3); bi3 = fmaf(c.w, V2.y, bi3);
        };

        const int g0 = (base - lo) >> 1;          // even
        auto LP = [&](int n, float4& lo4, float4& hi4) {
            int p = phys4(g0 - 2 * n);
            lo4 = wbase[p]; hi4 = wbase[p + 8];
        };

        float4 A0, A1, B0, B1, C0, C1, D0, D1;
        float4 E0, E1, F0, F1, G0, G1, H0, H1;
        LP(-1, A0, A1); LP(0, B0, B1); LP(1, C0, C1); LP(2, D0, D1);
        float4 cB = bj4[co], cC = bj4[co + 1], cD = bj4[co + 2];

        int bb = 0;
        while (bb + 8 <= nb) {
            LP(bb + 3, E0, E1); float4 cE = bj4[co + bb + 3];
            body(B0, B1, A0, A1, cB);
            LP(bb + 4, F0, F1); float4 cF = bj4[co + bb + 4];
            body(C0, C1, B0, B1, cC);
            LP(bb + 5, G0, G1); float4 cG = bj4[co + bb + 5];
            body(D0, D1, C0, C1, cD);
            LP(bb + 6, H0, H1); float4 cH = bj4[co + bb + 6];
            body(E0, E1, D0, D1, cE);
            LP(bb + 7, A0, A1); float4 cI = bj4[co + bb + 7];
            body(F0, F1, E0, E1, cF);
            LP(bb + 8, B0, B1); cB = bj4[co + bb + 8];
            body(G0, G1, F0, F1, cG);
            LP(bb + 9, C0, C1); cC = bj4[co + bb + 9];
            body(H0, H1, G0, G1, cH);
            LP(bb + 10, D0, D1); cD = bj4[co + bb + 10];
            body(A0, A1, H0, H1, cI);
            bb += 8;
        }
        int r = nb - bb;
        if (r > 0) { body(B0, B1, A0, A1, cB);
          if (r > 1) { body(C0, C1, B0, B1, cC);
            if (r > 2) { body(D0, D1, C0, C1, cD);
              if (r > 3) { LP(bb + 3, E0, E1); float4 cE = bj4[co + bb + 3];
                body(E0, E1, D0, D1, cE);
                if (r > 4) { LP(bb + 4, F0, F1); float4 cF = bj4[co + bb + 4];
                  body(F0, F1, E0, E1, cF);
                  if (r > 5) { LP(bb + 5, G0, G1); float4 cG = bj4[co + bb + 5];
                    body(G0, G1, F0, F1, cG);
                    if (r > 6) { LP(bb + 6, H0, H1); float4 cH = bj4[co + bb + 6];
                      body(H0, H1, G0, G1, cH); } } } } } } }

        #pragma unroll
        for (int h = 0; h < 16; ++h) {
            float we = W_e[(s * 16 + h) * 24 + j];
            float wi = W_i[(s * 16 + h) * 24 + j];
            z[h][0] = fmaf(we, be0, fmaf(wi, bi0, z[h][0]));
            z[h][1] = fmaf(we, be1, fmaf(wi, bi1, z[h][1]));
            z[h][2] = fmaf(we, be2, fmaf(wi, bi2, z[h][2]));
            z[h][3] = fmaf(we, be3, fmaf(wi, bi3, z[h][3]));
        }
    }

    float w2v[16];
    #pragma unroll
    for (int h = 0; h < 16; ++h) w2v[h] = __expf(W2[s * 16 + h]);

    #pragma unroll
    for (int k = 0; k < 4; ++k) {
        int t = t0 + 4 * tid + k;
        if (t < 5000) {
            float acc = 0.f;
            #pragma unroll
            for (int h = 0; h < 16; ++h) {
                float e2 = __expf(2.0f * z[h][k]);
                float th = 1.0f - 2.0f / (e2 + 1.0f);
                acc = fmaf(w2v[h], th, acc);
            }
            sub_out[((size_t)bz * 5000 + t) * 20 + s] = acc;
        }
    }
}

// ---------------------------------------------------------------------------
// final[b,t] = V_o + sum_s sub_out[b,t,s]
// ---------------------------------------------------------------------------
__global__ __launch_bounds__(256) void final_kernel(
    const float* __restrict__ sub_out, const float* __restrict__ V_o,
    float* __restrict__ fin)
{
    int r = blockIdx.x * 256 + threadIdx.x;
    if (r < 40000) {
        const float* p = sub_out + (size_t)r * 20;
        float a = V_o[0];
        #pragma unroll
        for (int s = 0; s < 20; ++s) a += p[s];
        fin[r] = a;
    }
}

extern "C" void kernel_launch(void* const* d_in, const int* in_sizes, int n_in,
                              void* d_out, int out_size, void* d_ws, size_t ws_size,
                              hipStream_t stream)
{
    const float* S_e     = (const float*)d_in[0];
    const float* S_i     = (const float*)d_in[1];
    const float* E_scale = (const float*)d_in[2];
    const float* I_scale = (const float*)d_in[3];
    const float* W_e     = (const float*)d_in[4];
    const float* W_i     = (const float*)d_in[5];
    const float* W2      = (const float*)d_in[6];
    const float* b1      = (const float*)d_in[7];
    const float* Ce_raw  = (const float*)d_in[8];
    const float* Ci_raw  = (const float*)d_in[9];
    const float* V_o     = (const float*)d_in[10];
    const float* temp    = (const float*)d_in[11];

    float* out     = (float*)d_out;
    float* fin     = out;              // 40000
    float* sub_out = out + 40000;      // 800000
    float* outCe   = out + 840000;     // 40000
    float* outCi   = out + 880000;     // 4000

    float* ws    = (float*)d_ws;
    float4* CbE  = (float4*)ws;        // 32 blk x 5 x 64 float4 = 40960 floats
    float4* CbI  = (float4*)(ws + 40960); // 4 blk x 5 x 64 = 5120 floats
    float* basis = ws + 46080;         // 24*404 = 9696
    float* syn_e = ws + 55776;         // 800000
    float* syn_i = ws + 855776;        // 800000

    prep_kernel<<<47, 256, 0, stream>>>(Ce_raw, Ci_raw, E_scale, I_scale, temp,
                                        CbE, CbI, basis, outCe, outCi);
    syn_kernel<32><<<2500, 256, 0, stream>>>(S_e, CbE, syn_e, 2000);
    syn_kernel<4><<<2500, 256, 0, stream>>>(S_i, CbI, syn_i, 200);
    conv_kernel<<<dim3(10, 20, 8), 128, 0, stream>>>(syn_e, syn_i, basis,
                                                     W_e, W_i, b1, W2, sub_out);
    final_kernel<<<157, 256, 0, stream>>>(sub_out, V_o, fin);
}

// Round 9
// 310.743 us; speedup vs baseline: 1.1955x; 1.1627x over previous
//
#include <hip/hip_runtime.h>
#include <math.h>

#define PI_F 3.14159265358979323846f
#define BSTRIDE 404   // basis row stride (400 taps + 4 zero pad)

// ---------------------------------------------------------------------------
// Prep: softmax over sub-axis (also to d_out), scaled-transposed CsT copies
// (zero-padded to 2048 / 256 rows), and the 24x404 masked cos-basis table.
// ---------------------------------------------------------------------------
__global__ __launch_bounds__(256) void prep_kernel(
    const float* __restrict__ Ce_raw, const float* __restrict__ Ci_raw,
    const float* __restrict__ Escale, const float* __restrict__ Iscale,
    const float* __restrict__ temp,
    float* __restrict__ CsT_e, float* __restrict__ CsT_i,
    float* __restrict__ basis,
    float* __restrict__ outCe, float* __restrict__ outCi)
{
    int id = blockIdx.x * 256 + threadIdx.x;
    if (id < 2000) {
        int e = id;
        float t = temp[0];
        float v[20];
        float m = -1e30f;
        #pragma unroll
        for (int s = 0; s < 20; ++s) { v[s] = Ce_raw[s * 2000 + e] / t; m = fmaxf(m, v[s]); }
        float sum = 0.f;
        #pragma unroll
        for (int s = 0; s < 20; ++s) { v[s] = expf(v[s] - m); sum += v[s]; }
        float inv = 1.f / sum;
        float sc = expf(Escale[e]);
        #pragma unroll
        for (int s = 0; s < 20; ++s) {
            float p = v[s] * inv;
            outCe[s * 2000 + e] = p;
            CsT_e[e * 20 + s] = p * sc;
        }
    } else if (id < 2200) {
        int e = id - 2000;
        float t = temp[0];
        float v[20];
        float m = -1e30f;
        #pragma unroll
        for (int s = 0; s < 20; ++s) { v[s] = Ci_raw[s * 200 + e] / t; m = fmaxf(m, v[s]); }
        float sum = 0.f;
        #pragma unroll
        for (int s = 0; s < 20; ++s) { v[s] = expf(v[s] - m); sum += v[s]; }
        float inv = 1.f / sum;
        float sc = expf(Iscale[e]);
        #pragma unroll
        for (int s = 0; s < 20; ++s) {
            float p = v[s] * inv;
            outCi[s * 200 + e] = p;
            CsT_i[e * 20 + s] = p * sc;
        }
    } else if (id < 2200 + 24 * BSTRIDE) {
        int idx = id - 2200;
        int j = idx / BSTRIDE, d = idx - j * BSTRIDE;
        float val = 0.f;
        if (d < 400) {
            float raw = 6.0f * logf((float)d + 1.0f + 1e-7f);
            float ph = (PI_F * 0.5f) * (float)j;
            if (raw >= ph - PI_F && raw <= ph + PI_F) val = 0.5f * cosf(raw - ph) + 0.5f;
        }
        basis[idx] = val;
    } else if (id < 11896 + 48) {               // CsT_e pad rows 2000..2047
        int row = 2000 + (id - 11896);
        #pragma unroll
        for (int s = 0; s < 20; ++s) CsT_e[row * 20 + s] = 0.f;
    } else if (id < 11944 + 56) {               // CsT_i pad rows 200..255
        int row = 200 + (id - 11944);
        #pragma unroll
        for (int s = 0; s < 20; ++s) CsT_i[row * 20 + s] = 0.f;
    }
}

// ---------------------------------------------------------------------------
// syn einsum (R3 structure, the empirical best): block = 64 rows x all e.
// Per 128-e chunk: coalesced float4 loads (lanes along e) -> padded LDS tile;
// wave w computes a wave-uniform 32-e quarter (CsT scalarizes to s_load),
// lane -> row. Partial reduce via red[(w*64+lane)*21+s]: stride 21 is coprime
// with 32 banks -> conflict-free (stride-80 layout was a 32-way conflict,
// SQ_LDS_BANK_CONFLICT=1.8e6 in R5).
// ---------------------------------------------------------------------------
template <int NCHUNK>
__global__ __launch_bounds__(256) void syn_kernel(
    const float* __restrict__ S, const float* __restrict__ CsT,
    float* __restrict__ syn, int Eno)
{
    __shared__ float4 tile[64 * 33];                       // 33792 B
    float* red = reinterpret_cast<float*>(tile);           // [4][64][21] alias
    const int tid = threadIdx.x;
    const int lane = tid & 63;
    const int w = __builtin_amdgcn_readfirstlane(tid >> 6);
    const int r0 = blockIdx.x * 64;

    float acc[20];
    #pragma unroll
    for (int s = 0; s < 20; ++s) acc[s] = 0.f;

    for (int ch = 0; ch < NCHUNK; ++ch) {
        const int ebase = ch * 128;
        #pragma unroll
        for (int i = 0; i < 8; ++i) {
            int f = tid + i * 256;
            int row = f >> 5, col4 = f & 31;
            int e0 = ebase + col4 * 4;
            float4 v = make_float4(0.f, 0.f, 0.f, 0.f);
            if (e0 + 4 <= Eno)
                v = *reinterpret_cast<const float4*>(S + (size_t)(r0 + row) * Eno + e0);
            tile[row * 33 + col4] = v;
        }
        __syncthreads();

        const float4* crow = reinterpret_cast<const float4*>(CsT + (size_t)(ebase + w * 32) * 20);
        #pragma unroll
        for (int c4 = 0; c4 < 8; ++c4) {
            float4 v = tile[lane * 33 + w * 8 + c4];
            const float4* ct = crow + c4 * 20;             // 4 e-rows x 5 float4
            float vv[4] = {v.x, v.y, v.z, v.w};
            #pragma unroll
            for (int q = 0; q < 4; ++q) {
                float sv = vv[q];
                #pragma unroll
                for (int c5 = 0; c5 < 5; ++c5) {
                    float4 cc = ct[q * 5 + c5];
                    acc[c5 * 4 + 0] = fmaf(sv, cc.x, acc[c5 * 4 + 0]);
                    acc[c5 * 4 + 1] = fmaf(sv, cc.y, acc[c5 * 4 + 1]);
                    acc[c5 * 4 + 2] = fmaf(sv, cc.z, acc[c5 * 4 + 2]);
                    acc[c5 * 4 + 3] = fmaf(sv, cc.w, acc[c5 * 4 + 3]);
                }
            }
        }
        __syncthreads();
    }

    #pragma unroll
    for (int s = 0; s < 20; ++s) red[(w * 64 + lane) * 21 + s] = acc[s];
    __syncthreads();

    #pragma unroll
    for (int i = 0; i < 5; ++i) {                          // p = s*64 + row
        int p = tid + i * 256;
        int row = p & 63, s = p >> 6;
        float a = red[(0 * 64 + row) * 21 + s] + red[(1 * 64 + row) * 21 + s]
                + red[(2 * 64 + row) * 21 + s] + red[(3 * 64 + row) * 21 + s];
        int r = r0 + row;
        int b = r / 5000, t = r - b * 5000;
        syn[((size_t)b * 20 + s) * 5000 + t] = a;          // coalesced per s
    }
}

// ---------------------------------------------------------------------------
// Fused basis-conv + layer1(tanh) + layer2 reduce.  (R5 unroll-8, best conv)
// Bit-rotate LDS swizzle phys4; two-bank pipeline, 3-body load lookahead.
// ---------------------------------------------------------------------------
__device__ const int CJ_LO[24] = {0,0,0,0,0,0,0,0,0,4,4,8,12,16,20,28,36,48,64,84,108,140,184,240};
__device__ const int CJ_NB[24] = {1,1,1,1,2,2,3,3,4,4,5,6,7,9,12,15,19,25,31,41,53,65,54,40};

__device__ __forceinline__ int phys4(int g) {
    return (g & ~15) | ((g >> 1) & 7) | ((g & 1) << 3);
}

__global__ __launch_bounds__(128) void conv_kernel(
    const float* __restrict__ syn_e, const float* __restrict__ syn_i,
    const float* __restrict__ basis,
    const float* __restrict__ W_e, const float* __restrict__ W_i,
    const float* __restrict__ b1, const float* __restrict__ W2,
    float* __restrict__ sub_out)
{
    __shared__ float4 win4[16 + 464];             // 16-granule guard + window
    float4* wbase = win4 + 16;
    float2* win2 = reinterpret_cast<float2*>(wbase);
    const int tid = threadIdx.x;
    const int tile = blockIdx.x, s = blockIdx.y, bz = blockIdx.z;
    const int t0 = tile * 512;

    const float* se = syn_e + ((size_t)bz * 20 + s) * 5000;
    const float* si = syn_i + ((size_t)bz * 20 + s) * 5000;
    for (int l = tid; l < 920; l += 128) {
        int t = t0 - 404 + l;
        float ve = 0.f, vi = 0.f;
        if ((unsigned)t < 5000u) { ve = se[t]; vi = si[t]; }
        int g = l >> 1;
        win2[2 * phys4(g) + (l & 1)] = make_float2(ve, vi);
    }
    __syncthreads();

    float z[16][4];
    #pragma unroll
    for (int h = 0; h < 16; ++h) {
        float bv = b1[s * 16 + h];
        #pragma unroll
        for (int k = 0; k < 4; ++k) z[h][k] = bv;
    }

    const int base = 4 * tid + 400;

    for (int j = 0; j < 24; ++j) {
        const float4* bj4 = reinterpret_cast<const float4*>(basis + j * BSTRIDE);
        const int lo = CJ_LO[j];
        const int nb = CJ_NB[j];
        const int co = lo >> 2;
        float be0 = 0.f, be1 = 0.f, be2 = 0.f, be3 = 0.f;
        float bi0 = 0.f, bi1 = 0.f, bi2 = 0.f, bi3 = 0.f;

        auto body = [&](const float4& V0, const float4& V1,
                        const float4& V2, const float4& V3, const float4& c) {
            be0 = fmaf(c.x, V2.x, be0); bi0 = fmaf(c.x, V2.y, bi0);
            be1 = fmaf(c.x, V2.z, be1); bi1 = fmaf(c.x, V2.w, bi1);
            be2 = fmaf(c.x, V3.x, be2); bi2 = fmaf(c.x, V3.y, bi2);
            be3 = fmaf(c.x, V3.z, be3); bi3 = fmaf(c.x, V3.w, bi3);
            be0 = fmaf(c.y, V1.z, be0); bi0 = fmaf(c.y, V1.w, bi0);
            be1 = fmaf(c.y, V2.x, be1); bi1 = fmaf(c.y, V2.y, bi1);
            be2 = fmaf(c.y, V2.z, be2); bi2 = fmaf(c.y, V2.w, bi2);
            be3 = fmaf(c.y, V3.x, be3); bi3 = fmaf(c.y, V3.y, bi3);
            be0 = fmaf(c.z, V1.x, be0); bi0 = fmaf(c.z, V1.y, bi0);
            be1 = fmaf(c.z, V1.z, be1); bi1 = fmaf(c.z, V1.w, bi1);
            be2 = fmaf(c.z, V2.x, be2); bi2 = fmaf(c.z, V2.y, bi2);
            be3 = fmaf(c.z, V2.z, be3); bi3 = fmaf(c.z, V2.w, bi3);
            be0 = fmaf(c.w, V0.z, be0); bi0 = fmaf(c.w, V0.w, bi0);
            be1 = fmaf(c.w, V1.x, be1); bi1 = fmaf(c.w, V1.y, bi1);
            be2 = fmaf(c.w, V1.z, be2); bi2 = fmaf(c.w, V1.w, bi2);
            be3 = fmaf(c.w, V2.x, be3); bi3 = fmaf(c.w, V2.y, bi3);
        };

        const int g0 = (base - lo) >> 1;          // even
        auto LP = [&](int n, float4& lo4, float4& hi4) {
            int p = phys4(g0 - 2 * n);
            lo4 = wbase[p]; hi4 = wbase[p + 8];
        };

        float4 A0, A1, B0, B1, C0, C1, D0, D1;
        float4 E0, E1, F0, F1, G0, G1, H0, H1;
        LP(-1, A0, A1); LP(0, B0, B1); LP(1, C0, C1); LP(2, D0, D1);
        float4 cB = bj4[co], cC = bj4[co + 1], cD = bj4[co + 2];

        int bb = 0;
        while (bb + 8 <= nb) {
            LP(bb + 3, E0, E1); float4 cE = bj4[co + bb + 3];
            body(B0, B1, A0, A1, cB);
            LP(bb + 4, F0, F1); float4 cF = bj4[co + bb + 4];
            body(C0, C1, B0, B1, cC);
            LP(bb + 5, G0, G1); float4 cG = bj4[co + bb + 5];
            body(D0, D1, C0, C1, cD);
            LP(bb + 6, H0, H1); float4 cH = bj4[co + bb + 6];
            body(E0, E1, D0, D1, cE);
            LP(bb + 7, A0, A1); float4 cI = bj4[co + bb + 7];
            body(F0, F1, E0, E1, cF);
            LP(bb + 8, B0, B1); cB = bj4[co + bb + 8];
            body(G0, G1, F0, F1, cG);
            LP(bb + 9, C0, C1); cC = bj4[co + bb + 9];
            body(H0, H1, G0, G1, cH);
            LP(bb + 10, D0, D1); cD = bj4[co + bb + 10];
            body(A0, A1, H0, H1, cI);
            bb += 8;
        }
        int r = nb - bb;
        if (r > 0) { body(B0, B1, A0, A1, cB);
          if (r > 1) { body(C0, C1, B0, B1, cC);
            if (r > 2) { body(D0, D1, C0, C1, cD);
              if (r > 3) { LP(bb + 3, E0, E1); float4 cE = bj4[co + bb + 3];
                body(E0, E1, D0, D1, cE);
                if (r > 4) { LP(bb + 4, F0, F1); float4 cF = bj4[co + bb + 4];
                  body(F0, F1, E0, E1, cF);
                  if (r > 5) { LP(bb + 5, G0, G1); float4 cG = bj4[co + bb + 5];
                    body(G0, G1, F0, F1, cG);
                    if (r > 6) { LP(bb + 6, H0, H1); float4 cH = bj4[co + bb + 6];
                      body(H0, H1, G0, G1, cH); } } } } } } }

        #pragma unroll
        for (int h = 0; h < 16; ++h) {
            float we = W_e[(s * 16 + h) * 24 + j];
            float wi = W_i[(s * 16 + h) * 24 + j];
            z[h][0] = fmaf(we, be0, fmaf(wi, bi0, z[h][0]));
            z[h][1] = fmaf(we, be1, fmaf(wi, bi1, z[h][1]));
            z[h][2] = fmaf(we, be2, fmaf(wi, bi2, z[h][2]));
            z[h][3] = fmaf(we, be3, fmaf(wi, bi3, z[h][3]));
        }
    }

    float w2v[16];
    #pragma unroll
    for (int h = 0; h < 16; ++h) w2v[h] = __expf(W2[s * 16 + h]);

    #pragma unroll
    for (int k = 0; k < 4; ++k) {
        int t = t0 + 4 * tid + k;
        if (t < 5000) {
            float acc = 0.f;
            #pragma unroll
            for (int h = 0; h < 16; ++h) {
                float e2 = __expf(2.0f * z[h][k]);
                float th = 1.0f - 2.0f / (e2 + 1.0f);
                acc = fmaf(w2v[h], th, acc);
            }
            sub_out[((size_t)bz * 5000 + t) * 20 + s] = acc;
        }
    }
}

// ---------------------------------------------------------------------------
// final[b,t] = V_o + sum_s sub_out[b,t,s]
// ---------------------------------------------------------------------------
__global__ __launch_bounds__(256) void final_kernel(
    const float* __restrict__ sub_out, const float* __restrict__ V_o,
    float* __restrict__ fin)
{
    int r = blockIdx.x * 256 + threadIdx.x;
    if (r < 40000) {
        const float* p = sub_out + (size_t)r * 20;
        float a = V_o[0];
        #pragma unroll
        for (int s = 0; s < 20; ++s) a += p[s];
        fin[r] = a;
    }
}

extern "C" void kernel_launch(void* const* d_in, const int* in_sizes, int n_in,
                              void* d_out, int out_size, void* d_ws, size_t ws_size,
                              hipStream_t stream)
{
    const float* S_e     = (const float*)d_in[0];
    const float* S_i     = (const float*)d_in[1];
    const float* E_scale = (const float*)d_in[2];
    const float* I_scale = (const float*)d_in[3];
    const float* W_e     = (const float*)d_in[4];
    const float* W_i     = (const float*)d_in[5];
    const float* W2      = (const float*)d_in[6];
    const float* b1      = (const float*)d_in[7];
    const float* Ce_raw  = (const float*)d_in[8];
    const float* Ci_raw  = (const float*)d_in[9];
    const float* V_o     = (const float*)d_in[10];
    const float* temp    = (const float*)d_in[11];

    float* out     = (float*)d_out;
    float* fin     = out;              // 40000
    float* sub_out = out + 40000;      // 800000
    float* outCe   = out + 840000;     // 40000
    float* outCi   = out + 880000;     // 4000

    float* ws    = (float*)d_ws;
    float* CsT_e = ws;                 // 2048*20 = 40960 (zero-padded)
    float* CsT_i = ws + 40960;         // 256*20  = 5120  (zero-padded)
    float* basis = ws + 46080;         // 24*404  = 9696
    float* syn_e = ws + 55776;         // 800000
    float* syn_i = ws + 855776;        // 800000

    prep_kernel<<<47, 256, 0, stream>>>(Ce_raw, Ci_raw, E_scale, I_scale, temp,
                                        CsT_e, CsT_i, basis, outCe, outCi);
    syn_kernel<16><<<625, 256, 0, stream>>>(S_e, CsT_e, syn_e, 2000);
    syn_kernel<2><<<625, 256, 0, stream>>>(S_i, CsT_i, syn_i, 200);
    conv_kernel<<<dim3(10, 20, 8), 128, 0, stream>>>(syn_e, syn_i, basis,
                                                     W_e, W_i, b1, W2, sub_out);
    final_kernel<<<157, 256, 0, stream>>>(sub_out, V_o, fin);
}

// Round 10
// 300.950 us; speedup vs baseline: 1.2344x; 1.0325x over previous
//
#include <hip/hip_runtime.h>
#include <math.h>

#define PI_F 3.14159265358979323846f
#define BSTRIDE 404   // basis row stride (400 taps + 4 zero pad)

// ---------------------------------------------------------------------------
// Prep: softmax over sub-axis (also to d_out), scaled-transposed CsT copies
// (zero-padded to 2048 / 256 rows), and the 24x404 masked cos-basis table.
// ---------------------------------------------------------------------------
__global__ __launch_bounds__(256) void prep_kernel(
    const float* __restrict__ Ce_raw, const float* __restrict__ Ci_raw,
    const float* __restrict__ Escale, const float* __restrict__ Iscale,
    const float* __restrict__ temp,
    float* __restrict__ CsT_e, float* __restrict__ CsT_i,
    float* __restrict__ basis,
    float* __restrict__ outCe, float* __restrict__ outCi)
{
    int id = blockIdx.x * 256 + threadIdx.x;
    if (id < 2000) {
        int e = id;
        float t = temp[0];
        float v[20];
        float m = -1e30f;
        #pragma unroll
        for (int s = 0; s < 20; ++s) { v[s] = Ce_raw[s * 2000 + e] / t; m = fmaxf(m, v[s]); }
        float sum = 0.f;
        #pragma unroll
        for (int s = 0; s < 20; ++s) { v[s] = expf(v[s] - m); sum += v[s]; }
        float inv = 1.f / sum;
        float sc = expf(Escale[e]);
        #pragma unroll
        for (int s = 0; s < 20; ++s) {
            float p = v[s] * inv;
            outCe[s * 2000 + e] = p;
            CsT_e[e * 20 + s] = p * sc;
        }
    } else if (id < 2200) {
        int e = id - 2000;
        float t = temp[0];
        float v[20];
        float m = -1e30f;
        #pragma unroll
        for (int s = 0; s < 20; ++s) { v[s] = Ci_raw[s * 200 + e] / t; m = fmaxf(m, v[s]); }
        float sum = 0.f;
        #pragma unroll
        for (int s = 0; s < 20; ++s) { v[s] = expf(v[s] - m); sum += v[s]; }
        float inv = 1.f / sum;
        float sc = expf(Iscale[e]);
        #pragma unroll
        for (int s = 0; s < 20; ++s) {
            float p = v[s] * inv;
            outCi[s * 200 + e] = p;
            CsT_i[e * 20 + s] = p * sc;
        }
    } else if (id < 2200 + 24 * BSTRIDE) {
        int idx = id - 2200;
        int j = idx / BSTRIDE, d = idx - j * BSTRIDE;
        float val = 0.f;
        if (d < 400) {
            float raw = 6.0f * logf((float)d + 1.0f + 1e-7f);
            float ph = (PI_F * 0.5f) * (float)j;
            if (raw >= ph - PI_F && raw <= ph + PI_F) val = 0.5f * cosf(raw - ph) + 0.5f;
        }
        basis[idx] = val;
    } else if (id < 11896 + 48) {               // CsT_e pad rows 2000..2047
        int row = 2000 + (id - 11896);
        #pragma unroll
        for (int s = 0; s < 20; ++s) CsT_e[row * 20 + s] = 0.f;
    } else if (id < 11944 + 56) {               // CsT_i pad rows 200..255
        int row = 200 + (id - 11944);
        #pragma unroll
        for (int s = 0; s < 20; ++s) CsT_i[row * 20 + s] = 0.f;
    }
}

// ---------------------------------------------------------------------------
// syn einsum, FUSED + E-SPLIT: grid z selects the slice --
//   z=0: S_e chunks 0..7   -> syn_eA (e 0..1023)
//   z=1: S_e chunks 8..15  -> syn_eB (e 1024..2047, zero-padded rows)
//   z=2: S_i chunks 0..1   -> syn_i
// 1875 blocks (~29 waves/CU avail, LDS-capped 16/CU) vs 625 before: halves
// each block's serial load->barrier->compute chain and doubles TLP.
// Core per-chunk structure = R3 empirical best. Partial-reduce layout
// red[(w*64+lane)*21+s]: stride 21 coprime 32 -> conflict-free both sides.
// ---------------------------------------------------------------------------
__global__ __launch_bounds__(256) void syn_kernel(
    const float* __restrict__ Se, const float* __restrict__ Si,
    const float* __restrict__ Ce, const float* __restrict__ Ci,
    float* __restrict__ outA, float* __restrict__ outB,
    float* __restrict__ outI)
{
    __shared__ float4 tile[64 * 33];                       // 33792 B
    float* red = reinterpret_cast<float*>(tile);           // [4][64][21] alias
    const int tid = threadIdx.x;
    const int lane = tid & 63;
    const int w = __builtin_amdgcn_readfirstlane(tid >> 6);
    const int r0 = blockIdx.x * 64;
    const int z = blockIdx.z;

    const float* S   = (z == 2) ? Si : Se;
    const float* CsT = (z == 2) ? Ci : Ce;
    float* out       = (z == 0) ? outA : (z == 1) ? outB : outI;
    const int Eno    = (z == 2) ? 200 : 2000;
    const int ch0    = (z == 1) ? 8 : 0;
    const int nch    = (z == 2) ? 2 : 8;

    float acc[20];
    #pragma unroll
    for (int s = 0; s < 20; ++s) acc[s] = 0.f;

    for (int cc = 0; cc < nch; ++cc) {
        const int ebase = (ch0 + cc) * 128;
        #pragma unroll
        for (int i = 0; i < 8; ++i) {
            int f = tid + i * 256;
            int row = f >> 5, col4 = f & 31;
            int e0 = ebase + col4 * 4;
            float4 v = make_float4(0.f, 0.f, 0.f, 0.f);
            if (e0 + 4 <= Eno)
                v = *reinterpret_cast<const float4*>(S + (size_t)(r0 + row) * Eno + e0);
            tile[row * 33 + col4] = v;
        }
        __syncthreads();

        const float4* crow = reinterpret_cast<const float4*>(CsT + (size_t)(ebase + w * 32) * 20);
        #pragma unroll
        for (int c4 = 0; c4 < 8; ++c4) {
            float4 v = tile[lane * 33 + w * 8 + c4];
            const float4* ct = crow + c4 * 20;             // 4 e-rows x 5 float4
            float vv[4] = {v.x, v.y, v.z, v.w};
            #pragma unroll
            for (int q = 0; q < 4; ++q) {
                float sv = vv[q];
                #pragma unroll
                for (int c5 = 0; c5 < 5; ++c5) {
                    float4 cc2 = ct[q * 5 + c5];
                    acc[c5 * 4 + 0] = fmaf(sv, cc2.x, acc[c5 * 4 + 0]);
                    acc[c5 * 4 + 1] = fmaf(sv, cc2.y, acc[c5 * 4 + 1]);
                    acc[c5 * 4 + 2] = fmaf(sv, cc2.z, acc[c5 * 4 + 2]);
                    acc[c5 * 4 + 3] = fmaf(sv, cc2.w, acc[c5 * 4 + 3]);
                }
            }
        }
        __syncthreads();
    }

    #pragma unroll
    for (int s = 0; s < 20; ++s) red[(w * 64 + lane) * 21 + s] = acc[s];
    __syncthreads();

    #pragma unroll
    for (int i = 0; i < 5; ++i) {                          // p = s*64 + row
        int p = tid + i * 256;
        int row = p & 63, s = p >> 6;
        float a = red[(0 * 64 + row) * 21 + s] + red[(1 * 64 + row) * 21 + s]
                + red[(2 * 64 + row) * 21 + s] + red[(3 * 64 + row) * 21 + s];
        int r = r0 + row;
        int b = r / 5000, t = r - b * 5000;
        out[((size_t)b * 20 + s) * 5000 + t] = a;          // coalesced per s
    }
}

// ---------------------------------------------------------------------------
// Fused basis-conv + layer1(tanh) + layer2 reduce.  (R5 unroll-8 pipeline)
// Window = syn_eA + syn_eB (e-split partials) paired with syn_i.
// Bit-rotate LDS swizzle phys4; two-bank pipeline, 3-body load lookahead.
// ---------------------------------------------------------------------------
__device__ const int CJ_LO[24] = {0,0,0,0,0,0,0,0,0,4,4,8,12,16,20,28,36,48,64,84,108,140,184,240};
__device__ const int CJ_NB[24] = {1,1,1,1,2,2,3,3,4,4,5,6,7,9,12,15,19,25,31,41,53,65,54,40};

__device__ __forceinline__ int phys4(int g) {
    return (g & ~15) | ((g >> 1) & 7) | ((g & 1) << 3);
}

__global__ __launch_bounds__(128) void conv_kernel(
    const float* __restrict__ syn_eA, const float* __restrict__ syn_eB,
    const float* __restrict__ syn_i, const float* __restrict__ basis,
    const float* __restrict__ W_e, const float* __restrict__ W_i,
    const float* __restrict__ b1, const float* __restrict__ W2,
    float* __restrict__ sub_out)
{
    __shared__ float4 win4[16 + 464];             // 16-granule guard + window
    float4* wbase = win4 + 16;
    float2* win2 = reinterpret_cast<float2*>(wbase);
    const int tid = threadIdx.x;
    const int tile = blockIdx.x, s = blockIdx.y, bz = blockIdx.z;
    const int t0 = tile * 512;

    const float* seA = syn_eA + ((size_t)bz * 20 + s) * 5000;
    const float* seB = syn_eB + ((size_t)bz * 20 + s) * 5000;
    const float* si  = syn_i  + ((size_t)bz * 20 + s) * 5000;
    for (int l = tid; l < 920; l += 128) {
        int t = t0 - 404 + l;
        float ve = 0.f, vi = 0.f;
        if ((unsigned)t < 5000u) { ve = seA[t] + seB[t]; vi = si[t]; }
        int g = l >> 1;
        win2[2 * phys4(g) + (l & 1)] = make_float2(ve, vi);
    }
    __syncthreads();

    float z[16][4];
    #pragma unroll
    for (int h = 0; h < 16; ++h) {
        float bv = b1[s * 16 + h];
        #pragma unroll
        for (int k = 0; k < 4; ++k) z[h][k] = bv;
    }

    const int base = 4 * tid + 400;

    for (int j = 0; j < 24; ++j) {
        const float4* bj4 = reinterpret_cast<const float4*>(basis + j * BSTRIDE);
        const int lo = CJ_LO[j];
        const int nb = CJ_NB[j];
        const int co = lo >> 2;
        float be0 = 0.f, be1 = 0.f, be2 = 0.f, be3 = 0.f;
        float bi0 = 0.f, bi1 = 0.f, bi2 = 0.f, bi3 = 0.f;

        auto body = [&](const float4& V0, const float4& V1,
                        const float4& V2, const float4& V3, const float4& c) {
            be0 = fmaf(c.x, V2.x, be0); bi0 = fmaf(c.x, V2.y, bi0);
            be1 = fmaf(c.x, V2.z, be1); bi1 = fmaf(c.x, V2.w, bi1);
            be2 = fmaf(c.x, V3.x, be2); bi2 = fmaf(c.x, V3.y, bi2);
            be3 = fmaf(c.x, V3.z, be3); bi3 = fmaf(c.x, V3.w, bi3);
            be0 = fmaf(c.y, V1.z, be0); bi0 = fmaf(c.y, V1.w, bi0);
            be1 = fmaf(c.y, V2.x, be1); bi1 = fmaf(c.y, V2.y, bi1);
            be2 = fmaf(c.y, V2.z, be2); bi2 = fmaf(c.y, V2.w, bi2);
            be3 = fmaf(c.y, V3.x, be3); bi3 = fmaf(c.y, V3.y, bi3);
            be0 = fmaf(c.z, V1.x, be0); bi0 = fmaf(c.z, V1.y, bi0);
            be1 = fmaf(c.z, V1.z, be1); bi1 = fmaf(c.z, V1.w, bi1);
            be2 = fmaf(c.z, V2.x, be2); bi2 = fmaf(c.z, V2.y, bi2);
            be3 = fmaf(c.z, V2.z, be3); bi3 = fmaf(c.z, V2.w, bi3);
            be0 = fmaf(c.w, V0.z, be0); bi0 = fmaf(c.w, V0.w, bi0);
            be1 = fmaf(c.w, V1.x, be1); bi1 = fmaf(c.w, V1.y, bi1);
            be2 = fmaf(c.w, V1.z, be2); bi2 = fmaf(c.w, V1.w, bi2);
            be3 = fmaf(c.w, V2.x, be3); bi3 = fmaf(c.w, V2.y, bi3);
        };

        const int g0 = (base - lo) >> 1;          // even
        auto LP = [&](int n, float4& lo4, float4& hi4) {
            int p = phys4(g0 - 2 * n);
            lo4 = wbase[p]; hi4 = wbase[p + 8];
        };

        float4 A0, A1, B0, B1, C0, C1, D0, D1;
        float4 E0, E1, F0, F1, G0, G1, H0, H1;
        LP(-1, A0, A1); LP(0, B0, B1); LP(1, C0, C1); LP(2, D0, D1);
        float4 cB = bj4[co], cC = bj4[co + 1], cD = bj4[co + 2];

        int bb = 0;
        while (bb + 8 <= nb) {
            LP(bb + 3, E0, E1); float4 cE = bj4[co + bb + 3];
            body(B0, B1, A0, A1, cB);
            LP(bb + 4, F0, F1); float4 cF = bj4[co + bb + 4];
            body(C0, C1, B0, B1, cC);
            LP(bb + 5, G0, G1); float4 cG = bj4[co + bb + 5];
            body(D0, D1, C0, C1, cD);
            LP(bb + 6, H0, H1); float4 cH = bj4[co + bb + 6];
            body(E0, E1, D0, D1, cE);
            LP(bb + 7, A0, A1); float4 cI = bj4[co + bb + 7];
            body(F0, F1, E0, E1, cF);
            LP(bb + 8, B0, B1); cB = bj4[co + bb + 8];
            body(G0, G1, F0, F1, cG);
            LP(bb + 9, C0, C1); cC = bj4[co + bb + 9];
            body(H0, H1, G0, G1, cH);
            LP(bb + 10, D0, D1); cD = bj4[co + bb + 10];
            body(A0, A1, H0, H1, cI);
            bb += 8;
        }
        int r = nb - bb;
        if (r > 0) { body(B0, B1, A0, A1, cB);
          if (r > 1) { body(C0, C1, B0, B1, cC);
            if (r > 2) { body(D0, D1, C0, C1, cD);
              if (r > 3) { LP(bb + 3, E0, E1); float4 cE = bj4[co + bb + 3];
                body(E0, E1, D0, D1, cE);
                if (r > 4) { LP(bb + 4, F0, F1); float4 cF = bj4[co + bb + 4];
                  body(F0, F1, E0, E1, cF);
                  if (r > 5) { LP(bb + 5, G0, G1); float4 cG = bj4[co + bb + 5];
                    body(G0, G1, F0, F1, cG);
                    if (r > 6) { LP(bb + 6, H0, H1); float4 cH = bj4[co + bb + 6];
                      body(H0, H1, G0, G1, cH); } } } } } } }

        #pragma unroll
        for (int h = 0; h < 16; ++h) {
            float we = W_e[(s * 16 + h) * 24 + j];
            float wi = W_i[(s * 16 + h) * 24 + j];
            z[h][0] = fmaf(we, be0, fmaf(wi, bi0, z[h][0]));
            z[h][1] = fmaf(we, be1, fmaf(wi, bi1, z[h][1]));
            z[h][2] = fmaf(we, be2, fmaf(wi, bi2, z[h][2]));
            z[h][3] = fmaf(we, be3, fmaf(wi, bi3, z[h][3]));
        }
    }

    float w2v[16];
    #pragma unroll
    for (int h = 0; h < 16; ++h) w2v[h] = __expf(W2[s * 16 + h]);

    #pragma unroll
    for (int k = 0; k < 4; ++k) {
        int t = t0 + 4 * tid + k;
        if (t < 5000) {
            float acc = 0.f;
            #pragma unroll
            for (int h = 0; h < 16; ++h) {
                float e2 = __expf(2.0f * z[h][k]);
                float th = 1.0f - 2.0f / (e2 + 1.0f);
                acc = fmaf(w2v[h], th, acc);
            }
            sub_out[((size_t)bz * 5000 + t) * 20 + s] = acc;
        }
    }
}

// ---------------------------------------------------------------------------
// final[b,t] = V_o + sum_s sub_out[b,t,s]
// ---------------------------------------------------------------------------
__global__ __launch_bounds__(256) void final_kernel(
    const float* __restrict__ sub_out, const float* __restrict__ V_o,
    float* __restrict__ fin)
{
    int r = blockIdx.x * 256 + threadIdx.x;
    if (r < 40000) {
        const float* p = sub_out + (size_t)r * 20;
        float a = V_o[0];
        #pragma unroll
        for (int s = 0; s < 20; ++s) a += p[s];
        fin[r] = a;
    }
}

extern "C" void kernel_launch(void* const* d_in, const int* in_sizes, int n_in,
                              void* d_out, int out_size, void* d_ws, size_t ws_size,
                              hipStream_t stream)
{
    const float* S_e     = (const float*)d_in[0];
    const float* S_i     = (const float*)d_in[1];
    const float* E_scale = (const float*)d_in[2];
    const float* I_scale = (const float*)d_in[3];
    const float* W_e     = (const float*)d_in[4];
    const float* W_i     = (const float*)d_in[5];
    const float* W2      = (const float*)d_in[6];
    const float* b1      = (const float*)d_in[7];
    const float* Ce_raw  = (const float*)d_in[8];
    const float* Ci_raw  = (const float*)d_in[9];
    const float* V_o     = (const float*)d_in[10];
    const float* temp    = (const float*)d_in[11];

    float* out     = (float*)d_out;
    float* fin     = out;              // 40000
    float* sub_out = out + 40000;      // 800000
    float* outCe   = out + 840000;     // 40000
    float* outCi   = out + 880000;     // 4000

    float* ws     = (float*)d_ws;
    float* CsT_e  = ws;                // 2048*20 = 40960 (zero-padded)
    float* CsT_i  = ws + 40960;        // 256*20  = 5120  (zero-padded)
    float* basis  = ws + 46080;        // 24*404  = 9696
    float* syn_eA = ws + 55776;        // 800000  (e 0..1023 partial)
    float* syn_eB = ws + 855776;       // 800000  (e 1024..2047 partial)
    float* syn_i  = ws + 1655776;      // 800000

    prep_kernel<<<47, 256, 0, stream>>>(Ce_raw, Ci_raw, E_scale, I_scale, temp,
                                        CsT_e, CsT_i, basis, outCe, outCi);
    syn_kernel<<<dim3(625, 1, 3), 256, 0, stream>>>(S_e, S_i, CsT_e, CsT_i,
                                                    syn_eA, syn_eB, syn_i);
    conv_kernel<<<dim3(10, 20, 8), 128, 0, stream>>>(syn_eA, syn_eB, syn_i, basis,
                                                     W_e, W_i, b1, W2, sub_out);
    final_kernel<<<157, 256, 0, stream>>>(sub_out, V_o, fin);
}